// Round 16
// baseline (330.227 us; speedup 1.0000x reference)
//
#include <hip/hip_runtime.h>
#include <hip/hip_bf16.h>

// VQ-VAE forward, B=64, F=16.  ALL I/O float32 (d_out = float*: decoded 4194304 f32, indices 262144 f32).
// ws layout: f1 (64 MiB) | f2 (16 MiB) | f3 (16 MiB) = 96 MiB.
// R16: "conv1-shape" everywhere — per-thread state <= ~24 regs, block-uniform weight addrs (SGPR),
//      >= 8 blocks/CU. tconv1 = per-pixel x 4 parity classes (template<DY,DX>, 4096 blocks).
//      res = oc-split halves (2048 blocks, 8 acc). conv2 oc-split (R15). conv1/vq/tconv2 unchanged.
// Evidence: VGPR_Count=24 vs 32 live accs + clean HBM => compiler rematerializes through L2 when
//      state exceeds its target; only small-state high-occupancy kernels run near 2x FMA floor.

#define R16X(M) M(0) M(1) M(2) M(3) M(4) M(5) M(6) M(7) M(8) M(9) M(10) M(11) M(12) M(13) M(14) M(15)
#define R8X(M)  M(0) M(1) M(2) M(3) M(4) M(5) M(6) M(7)

// ---------------- conv1: 1->16, 256->128 (healthy reference shape) ----------------
__global__ __launch_bounds__(256) void conv1_k(const float* __restrict__ x, const float* __restrict__ w,
                                               const float* __restrict__ bias, float* __restrict__ out) {
    int idx = blockIdx.x * 256 + threadIdx.x;   // 64*128*128
    int ox = idx & 127;
    int oy = (idx >> 7) & 127;
    int b  = idx >> 14;
    const float* xin = x + (size_t)b * 65536;
    float pv[16];
#pragma unroll
    for (int ky = 0; ky < 4; ++ky) {
        int iy = 2 * oy - 1 + ky;
#pragma unroll
        for (int kx = 0; kx < 4; ++kx) {
            int ix = 2 * ox - 1 + kx;
            pv[ky * 4 + kx] = (iy >= 0 && iy < 256 && ix >= 0 && ix < 256)
                                  ? xin[iy * 256 + ix] : 0.f;
        }
    }
    float* o = out + (size_t)b * (16 * 16384) + oy * 128 + ox;
#pragma unroll
    for (int oc = 0; oc < 16; ++oc) {
        float acc = bias[oc];
#pragma unroll
        for (int k = 0; k < 16; ++k) acc = fmaf(pv[k], w[oc * 16 + k], acc);
        o[oc * 16384] = fmaxf(acc, 0.f);
    }
}

// ---------------- conv2: 16->16, 128->64 — oc-halved, 2048 blocks ----------------
__global__ __launch_bounds__(256) void conv2_k(const float* __restrict__ in, const float* __restrict__ w,
                                               const float* __restrict__ bias, float* __restrict__ out) {
    int half = blockIdx.x >> 10;
    int idx  = (blockIdx.x & 1023) * 256 + threadIdx.x;   // 64*64*64
    int ox = idx & 63;
    int oy = (idx >> 6) & 63;
    int b  = idx >> 12;
    int ocb = half * 8;
    const float* xin = in + (size_t)b * (16 * 16384);
    const float* wb  = w + ocb * 256;
#define DECLA(i) float a##i = bias[ocb + i];
    R8X(DECLA)
#undef DECLA
    int iy0 = 2 * oy - 1, ix0 = 2 * ox - 1;
    bool y0ok = (iy0 >= 0), y3ok = (iy0 + 3 < 128);
    bool x0ok = (ix0 >= 0), x3ok = (ix0 + 3 < 128);
    for (int ic = 0; ic < 16; ++ic) {
        const float* xc = xin + ic * 16384 + iy0 * 128 + ix0;
        float p0  = (y0ok && x0ok) ? xc[0]       : 0.f;
        float p1  =  y0ok          ? xc[1]       : 0.f;
        float p2  =  y0ok          ? xc[2]       : 0.f;
        float p3  = (y0ok && x3ok) ? xc[3]       : 0.f;
        float p4  =  x0ok          ? xc[128 + 0] : 0.f;
        float p5  =                  xc[128 + 1];
        float p6  =                  xc[128 + 2];
        float p7  =  x3ok          ? xc[128 + 3] : 0.f;
        float p8  =  x0ok          ? xc[256 + 0] : 0.f;
        float p9  =                  xc[256 + 1];
        float p10 =                  xc[256 + 2];
        float p11 =  x3ok          ? xc[256 + 3] : 0.f;
        float p12 = (y3ok && x0ok) ? xc[384 + 0] : 0.f;
        float p13 =  y3ok          ? xc[384 + 1] : 0.f;
        float p14 =  y3ok          ? xc[384 + 2] : 0.f;
        float p15 = (y3ok && x3ok) ? xc[384 + 3] : 0.f;
        const float* wp = wb + ic * 16;
#define FMAOC(oc) { const float* q = wp + oc * 256; \
        a##oc = fmaf(p0,  q[0],  a##oc); a##oc = fmaf(p1,  q[1],  a##oc); \
        a##oc = fmaf(p2,  q[2],  a##oc); a##oc = fmaf(p3,  q[3],  a##oc); \
        a##oc = fmaf(p4,  q[4],  a##oc); a##oc = fmaf(p5,  q[5],  a##oc); \
        a##oc = fmaf(p6,  q[6],  a##oc); a##oc = fmaf(p7,  q[7],  a##oc); \
        a##oc = fmaf(p8,  q[8],  a##oc); a##oc = fmaf(p9,  q[9],  a##oc); \
        a##oc = fmaf(p10, q[10], a##oc); a##oc = fmaf(p11, q[11], a##oc); \
        a##oc = fmaf(p12, q[12], a##oc); a##oc = fmaf(p13, q[13], a##oc); \
        a##oc = fmaf(p14, q[14], a##oc); a##oc = fmaf(p15, q[15], a##oc); }
        R8X(FMAOC)
#undef FMAOC
    }
    float* o = out + (size_t)b * (16 * 4096) + (size_t)ocb * 4096 + oy * 64 + ox;
#define STO(oc) o[oc * 4096] = fmaxf(a##oc, 0.f);
    R8X(STO)
#undef STO
}

// ---------------- residual block — oc-split halves, 2048 blocks, 8 acc/thread ----------------
__global__ __launch_bounds__(256) void res_k(const float* __restrict__ in, const float* __restrict__ w,
                                             const float* __restrict__ bias, float* __restrict__ out) {
    int half = blockIdx.x >> 10;
    int idx  = (blockIdx.x & 1023) * 256 + threadIdx.x;   // 64*64*64
    int ox = idx & 63;
    int oy = (idx >> 6) & 63;
    int b  = idx >> 12;
    int ocb = half * 8;
    const float* xin = in + (size_t)b * 65536;
    const float* wb  = w + (size_t)ocb * 144;
#define DECLB(i) float a##i = bias[ocb + i];
    R8X(DECLB)
#undef DECLB
    bool yt = (oy > 0), yb = (oy < 63);
    bool xl = (ox > 0), xr = (ox < 63);
    for (int ic = 0; ic < 16; ++ic) {
        const float* xb = xin + ic * 4096 + (oy - 1) * 64 + (ox - 1);
        float pa0 = (yt && xl) ? xb[0]       : 0.f;
        float pa1 =  yt        ? xb[1]       : 0.f;
        float pa2 = (yt && xr) ? xb[2]       : 0.f;
        float pb0 =  xl        ? xb[64 + 0]  : 0.f;
        float pb1 =              xb[64 + 1];
        float pb2 =  xr        ? xb[64 + 2]  : 0.f;
        float pc0 = (yb && xl) ? xb[128 + 0] : 0.f;
        float pc1 =  yb        ? xb[128 + 1] : 0.f;
        float pc2 = (yb && xr) ? xb[128 + 2] : 0.f;
        const float* wp = wb + ic * 9;
#define FMAR(oc) { const float* q = wp + oc * 144; \
        a##oc = fmaf(pa0, q[0], a##oc); a##oc = fmaf(pa1, q[1], a##oc); a##oc = fmaf(pa2, q[2], a##oc); \
        a##oc = fmaf(pb0, q[3], a##oc); a##oc = fmaf(pb1, q[4], a##oc); a##oc = fmaf(pb2, q[5], a##oc); \
        a##oc = fmaf(pc0, q[6], a##oc); a##oc = fmaf(pc1, q[7], a##oc); a##oc = fmaf(pc2, q[8], a##oc); }
        R8X(FMAR)
#undef FMAR
    }
    float* o        = out + (size_t)b * 65536 + (size_t)ocb * 4096 + oy * 64 + ox;
    const float* rr = xin + (size_t)ocb * 4096 + oy * 64 + ox;
#define RSTO(oc) o[oc * 4096] = rr[oc * 4096] + fmaxf(a##oc, 0.f);
    R8X(RSTO)
#undef RSTO
}

// ---------------- VQ: rows of 16 contiguous floats (raw NCHW flatten), K=64 ----------------
__global__ __launch_bounds__(256) void vq_k(const float* __restrict__ h, const float* __restrict__ cb,
                                            float* __restrict__ q, float* __restrict__ idx_out) {
    __shared__ float cbs[1024];  // 64 x 16
    __shared__ float cn[64];
    for (int i = threadIdx.x; i < 1024; i += 256) cbs[i] = cb[i];
    __syncthreads();
    if (threadIdx.x < 64) {
        float s = 0.f;
#pragma unroll
        for (int d = 0; d < 16; ++d) { float v = cbs[threadIdx.x * 16 + d]; s = fmaf(v, v, s); }
        cn[threadIdx.x] = s;
    }
    __syncthreads();
    int r = blockIdx.x * 256 + threadIdx.x;   // 262144 rows
    float f[16];
    const float4* hp = (const float4*)(h + (size_t)r * 16);
#pragma unroll
    for (int j = 0; j < 4; ++j) {
        float4 v = hp[j];
        f[j * 4 + 0] = v.x; f[j * 4 + 1] = v.y; f[j * 4 + 2] = v.z; f[j * 4 + 3] = v.w;
    }
    float best = 3.4e38f;
    int bi = 0;
    for (int k = 0; k < 64; ++k) {
        float dot = 0.f;
#pragma unroll
        for (int d = 0; d < 16; ++d) dot = fmaf(f[d], cbs[k * 16 + d], dot);
        float dist = cn[k] - 2.f * dot;   // +||f||^2 is per-row constant, argmin-invariant
        if (dist < best) { best = dist; bi = k; }
    }
    float4* qp = (float4*)(q + (size_t)r * 16);
    const float4* cp = (const float4*)(cbs + bi * 16);
#pragma unroll
    for (int j = 0; j < 4; ++j) qp[j] = cp[j];
    idx_out[r] = (float)bi;
}

// ---------------- tconv1: ConvTranspose2d 16->16, k4 s2 p1, 64->128, relu ----------------
// Per-pixel, 4 parity classes (block-uniform template<DY,DX>): 16 acc + 4 patch loads/ic,
// class-literal weight offsets -> SGPR; 4096 blocks (16/CU). CHANNEL-LAST out.
template <int DY, int DX>
__device__ __forceinline__ void tconv1_body(const float* __restrict__ xin, const float* __restrict__ w1,
                                            const float* __restrict__ bia, float* __restrict__ out,
                                            int b, int u, int v) {
#define TDECL(oc) float a##oc = bia[oc];
    R16X(TDECL)
#undef TDECL
    int jy0 = u + DY - 1, jy1 = u + DY;
    int jx0 = v + DX - 1, jx1 = v + DX;
    bool y0 = (jy0 >= 0), y1 = (jy1 < 64);
    bool x0 = (jx0 >= 0), x1 = (jx1 < 64);
    for (int ic = 0; ic < 16; ++ic) {
        const float* xc = xin + ic * 4096;
        const float* r0 = xc + jy0 * 64;
        const float* r1 = xc + jy1 * 64;
        float p00 = (y0 && x0) ? r0[jx0] : 0.f;
        float p01 = (y0 && x1) ? r0[jx1] : 0.f;
        float p10 = (y1 && x0) ? r1[jx0] : 0.f;
        float p11 = (y1 && x1) ? r1[jx1] : 0.f;
        const float* wic = w1 + ic * 256;    // (ic,oc,4,4)
#define TF(oc) { const float* q = wic + oc * 16; \
        a##oc = fmaf(p00, q[(3 - DY) * 4 + (3 - DX)], a##oc); \
        a##oc = fmaf(p01, q[(3 - DY) * 4 + (1 - DX)], a##oc); \
        a##oc = fmaf(p10, q[(1 - DY) * 4 + (3 - DX)], a##oc); \
        a##oc = fmaf(p11, q[(1 - DY) * 4 + (1 - DX)], a##oc); }
        R16X(TF)
#undef TF
    }
    int my = 2 * u + DY, mx = 2 * v + DX;
    float4* o = (float4*)(out + (((size_t)b * 16384) + my * 128 + mx) * 16);
    float4 s;
    s.x = fmaxf(a0,  0.f); s.y = fmaxf(a1,  0.f); s.z = fmaxf(a2,  0.f); s.w = fmaxf(a3,  0.f); o[0] = s;
    s.x = fmaxf(a4,  0.f); s.y = fmaxf(a5,  0.f); s.z = fmaxf(a6,  0.f); s.w = fmaxf(a7,  0.f); o[1] = s;
    s.x = fmaxf(a8,  0.f); s.y = fmaxf(a9,  0.f); s.z = fmaxf(a10, 0.f); s.w = fmaxf(a11, 0.f); o[2] = s;
    s.x = fmaxf(a12, 0.f); s.y = fmaxf(a13, 0.f); s.z = fmaxf(a14, 0.f); s.w = fmaxf(a15, 0.f); o[3] = s;
}

__global__ __launch_bounds__(256) void tconv1_k(const float* __restrict__ in,
                                                const float* __restrict__ w1, const float* __restrict__ bia,
                                                float* __restrict__ out) {
    int cls = blockIdx.x & 3;                    // block-uniform parity class
    int idx = (blockIdx.x >> 2) * 256 + threadIdx.x;   // 64 img * 64 u * 64 v
    int v = idx & 63;
    int u = (idx >> 6) & 63;
    int b = idx >> 12;
    const float* xin = in + (size_t)b * 65536;   // (16,64,64) channel-first
    if      (cls == 0) tconv1_body<0, 0>(xin, w1, bia, out, b, u, v);
    else if (cls == 1) tconv1_body<1, 0>(xin, w1, bia, out, b, u, v);
    else if (cls == 2) tconv1_body<0, 1>(xin, w1, bia, out, b, u, v);
    else               tconv1_body<1, 1>(xin, w1, bia, out, b, u, v);
}

// ---------------- tconv2: ConvTranspose2d 16->1, k4 s2 p1, 128->256 ----------------
#define P2 20
__global__ __launch_bounds__(256) void tconv2_k(const float* __restrict__ f1,
                                                const float* __restrict__ w2, const float* __restrict__ b2,
                                                float* __restrict__ out) {
    __shared__ float s1[324 * P2];       // [pixel(18x18)][16 ch + pad4]
    __shared__ float ws2[256];           // (ic,1,4,4)
    __shared__ float b2s;
    if (threadIdx.x < 256) ws2[threadIdx.x] = w2[threadIdx.x];
    if (threadIdx.x == 0) b2s = b2[0];

    int tile = blockIdx.x & 63;
    int b    = blockIdx.x >> 6;
    int Y0 = (tile >> 3) * 32;
    int X0 = (tile & 7) * 32;
    int m0 = (Y0 >> 1) - 1;
    int n0 = (X0 >> 1) - 1;
    const float* fb = f1 + (size_t)b * 262144;   // (128,128,16) channel-last

    for (int i = threadIdx.x; i < 5184; i += 256) {
        int p  = i >> 4;
        int ic = i & 15;
        int my = m0 + p / 18;
        int mx = n0 + p % 18;
        float v = 0.f;
        if (my >= 0 && my < 128 && mx >= 0 && mx < 128)
            v = fb[((size_t)(my * 128 + mx)) * 16 + ic];
        s1[p * P2 + ic] = v;
    }
    __syncthreads();

    int ly0 = threadIdx.x >> 5;
    int lx  = threadIdx.x & 31;
    int gx  = X0 + lx;
    int kyb = (Y0 + ly0 + 1) & 1;
    int kxb = (gx + 1) & 1;
    float wr[2][2][16];
#pragma unroll
    for (int a = 0; a < 2; ++a) {
#pragma unroll
        for (int c = 0; c < 2; ++c) {
            int ky = kyb + 2 * a, kx = kxb + 2 * c;
#pragma unroll
            for (int ic = 0; ic < 16; ++ic)
                wr[a][c][ic] = ws2[ic * 16 + ky * 4 + kx];
        }
    }
    int sx[2];
#pragma unroll
    for (int c = 0; c < 2; ++c) sx[c] = ((gx + 1 - (kxb + 2 * c)) >> 1) - n0;

#pragma unroll
    for (int r = 0; r < 4; ++r) {
        int gy = Y0 + ly0 + 8 * r;
        float acc = b2s;
#pragma unroll
        for (int a = 0; a < 2; ++a) {
            int sy = ((gy + 1 - (kyb + 2 * a)) >> 1) - m0;
#pragma unroll
            for (int c = 0; c < 2; ++c) {
                const float4* sp4 = (const float4*)&s1[(sy * 18 + sx[c]) * P2];
#pragma unroll
                for (int j = 0; j < 4; ++j) {
                    float4 v = sp4[j];
                    acc = fmaf(v.x, wr[a][c][j * 4 + 0], acc);
                    acc = fmaf(v.y, wr[a][c][j * 4 + 1], acc);
                    acc = fmaf(v.z, wr[a][c][j * 4 + 2], acc);
                    acc = fmaf(v.w, wr[a][c][j * 4 + 3], acc);
                }
            }
        }
        out[(size_t)b * 65536 + gy * 256 + gx] = acc;
    }
}

extern "C" void kernel_launch(void* const* d_in, const int* in_sizes, int n_in,
                              void* d_out, int out_size, void* d_ws, size_t ws_size,
                              hipStream_t stream) {
    const float* x    = (const float*)d_in[0];
    const float* c1w  = (const float*)d_in[1];
    const float* c1b  = (const float*)d_in[2];
    const float* c2w  = (const float*)d_in[3];
    const float* c2b  = (const float*)d_in[4];
    const float* er1w = (const float*)d_in[5];
    const float* er1b = (const float*)d_in[6];
    const float* er2w = (const float*)d_in[7];
    const float* er2b = (const float*)d_in[8];
    const float* cb   = (const float*)d_in[9];
    const float* dr1w = (const float*)d_in[10];
    const float* dr1b = (const float*)d_in[11];
    const float* dr2w = (const float*)d_in[12];
    const float* dr2b = (const float*)d_in[13];
    const float* t1w  = (const float*)d_in[14];
    const float* t1b  = (const float*)d_in[15];
    const float* t2w  = (const float*)d_in[16];
    const float* t2b  = (const float*)d_in[17];

    float* f1 = (float*)d_ws;                                // 64 MiB: dec ch-last
    float* f2 = (float*)((char*)d_ws + 67108864);            // (64,16,64,64)
    float* f3 = (float*)((char*)d_ws + 67108864 + 16777216); // (64,16,64,64)

    float* out     = (float*)d_out;                          // decoded: 4,194,304 f32
    float* idx_out = out + 4194304;                          // indices: 262,144 f32

    conv1_k <<<4096, 256, 0, stream>>>(x, c1w, c1b, f1);
    conv2_k <<<2048, 256, 0, stream>>>(f1, c2w, c2b, f2);
    res_k   <<<2048, 256, 0, stream>>>(f2, er1w, er1b, f3);  // er1
    res_k   <<<2048, 256, 0, stream>>>(f3, er2w, er2b, f2);  // er2
    vq_k    <<<1024, 256, 0, stream>>>(f2, cb, f3, idx_out); // quantized -> f3
    res_k   <<<2048, 256, 0, stream>>>(f3, dr1w, dr1b, f2);  // dr1
    res_k   <<<2048, 256, 0, stream>>>(f2, dr2w, dr2b, f3);  // dr2
    tconv1_k<<<4096, 256, 0, stream>>>(f3, t1w, t1b, f1);
    tconv2_k<<<4096, 256, 0, stream>>>(f1, t2w, t2b, out);
}

// Round 17
// 286.626 us; speedup vs baseline: 1.1521x; 1.1521x over previous
//
#include <hip/hip_runtime.h>
#include <hip/hip_bf16.h>

// VQ-VAE forward, B=64, F=16.  ALL I/O float32 (d_out = float*: decoded 4194304 f32, indices 262144 f32).
// ws layout: f1 (64 MiB) | f2 (16 MiB) | f3 (16 MiB) = 96 MiB.
// R17: tconv1 -> MFMA (mfma_f32_16x16x32_bf16). Per parity class (DY,DX): GEMM M=262144,N=16,K=64
//      (k = tap*16+ic). dr2 res writes bf16 CHANNEL-LAST into f3 region (decoder-only precision;
//      threshold 1.2 >> expected bf16 error ~0.05). Scalar-conv path for tconv1 was pinned at
//      ~76us across 6 variants (VALU issue == FMA-only time, VGPR report < live accs).
// Lessons: stage once barrier once (R8); uniform weights -> SGPR (R10); this toolchain caps
//      scalar-conv issue efficiency ~20% for 16-acc kernels (R11-R16) -> use the matrix pipe.

#define R16X(M) M(0) M(1) M(2) M(3) M(4) M(5) M(6) M(7) M(8) M(9) M(10) M(11) M(12) M(13) M(14) M(15)
#define R8X(M)  M(0) M(1) M(2) M(3) M(4) M(5) M(6) M(7)

typedef __attribute__((ext_vector_type(8))) short      bf16x8;
typedef __attribute__((ext_vector_type(8))) unsigned short u16x8;
typedef __attribute__((ext_vector_type(4))) float      f32x4;

__device__ __forceinline__ unsigned short f2bf(float f) {   // RNE fp32 -> bf16 bits
    unsigned u; __builtin_memcpy(&u, &f, 4);
    unsigned r = u + 0x7FFFu + ((u >> 16) & 1u);
    return (unsigned short)(r >> 16);
}

// ---------------- conv1: 1->16, 256->128 ----------------
__global__ __launch_bounds__(256) void conv1_k(const float* __restrict__ x, const float* __restrict__ w,
                                               const float* __restrict__ bias, float* __restrict__ out) {
    int idx = blockIdx.x * 256 + threadIdx.x;   // 64*128*128
    int ox = idx & 127;
    int oy = (idx >> 7) & 127;
    int b  = idx >> 14;
    const float* xin = x + (size_t)b * 65536;
    float pv[16];
#pragma unroll
    for (int ky = 0; ky < 4; ++ky) {
        int iy = 2 * oy - 1 + ky;
#pragma unroll
        for (int kx = 0; kx < 4; ++kx) {
            int ix = 2 * ox - 1 + kx;
            pv[ky * 4 + kx] = (iy >= 0 && iy < 256 && ix >= 0 && ix < 256)
                                  ? xin[iy * 256 + ix] : 0.f;
        }
    }
    float* o = out + (size_t)b * (16 * 16384) + oy * 128 + ox;
#pragma unroll
    for (int oc = 0; oc < 16; ++oc) {
        float acc = bias[oc];
#pragma unroll
        for (int k = 0; k < 16; ++k) acc = fmaf(pv[k], w[oc * 16 + k], acc);
        o[oc * 16384] = fmaxf(acc, 0.f);
    }
}

// ---------------- conv2: 16->16, 128->64 — oc-halved, 2048 blocks ----------------
__global__ __launch_bounds__(256) void conv2_k(const float* __restrict__ in, const float* __restrict__ w,
                                               const float* __restrict__ bias, float* __restrict__ out) {
    int half = blockIdx.x >> 10;
    int idx  = (blockIdx.x & 1023) * 256 + threadIdx.x;   // 64*64*64
    int ox = idx & 63;
    int oy = (idx >> 6) & 63;
    int b  = idx >> 12;
    int ocb = half * 8;
    const float* xin = in + (size_t)b * (16 * 16384);
    const float* wb  = w + ocb * 256;
#define DECLA(i) float a##i = bias[ocb + i];
    R8X(DECLA)
#undef DECLA
    int iy0 = 2 * oy - 1, ix0 = 2 * ox - 1;
    bool y0ok = (iy0 >= 0), y3ok = (iy0 + 3 < 128);
    bool x0ok = (ix0 >= 0), x3ok = (ix0 + 3 < 128);
    for (int ic = 0; ic < 16; ++ic) {
        const float* xc = xin + ic * 16384 + iy0 * 128 + ix0;
        float p0  = (y0ok && x0ok) ? xc[0]       : 0.f;
        float p1  =  y0ok          ? xc[1]       : 0.f;
        float p2  =  y0ok          ? xc[2]       : 0.f;
        float p3  = (y0ok && x3ok) ? xc[3]       : 0.f;
        float p4  =  x0ok          ? xc[128 + 0] : 0.f;
        float p5  =                  xc[128 + 1];
        float p6  =                  xc[128 + 2];
        float p7  =  x3ok          ? xc[128 + 3] : 0.f;
        float p8  =  x0ok          ? xc[256 + 0] : 0.f;
        float p9  =                  xc[256 + 1];
        float p10 =                  xc[256 + 2];
        float p11 =  x3ok          ? xc[256 + 3] : 0.f;
        float p12 = (y3ok && x0ok) ? xc[384 + 0] : 0.f;
        float p13 =  y3ok          ? xc[384 + 1] : 0.f;
        float p14 =  y3ok          ? xc[384 + 2] : 0.f;
        float p15 = (y3ok && x3ok) ? xc[384 + 3] : 0.f;
        const float* wp = wb + ic * 16;
#define FMAOC(oc) { const float* q = wp + oc * 256; \
        a##oc = fmaf(p0,  q[0],  a##oc); a##oc = fmaf(p1,  q[1],  a##oc); \
        a##oc = fmaf(p2,  q[2],  a##oc); a##oc = fmaf(p3,  q[3],  a##oc); \
        a##oc = fmaf(p4,  q[4],  a##oc); a##oc = fmaf(p5,  q[5],  a##oc); \
        a##oc = fmaf(p6,  q[6],  a##oc); a##oc = fmaf(p7,  q[7],  a##oc); \
        a##oc = fmaf(p8,  q[8],  a##oc); a##oc = fmaf(p9,  q[9],  a##oc); \
        a##oc = fmaf(p10, q[10], a##oc); a##oc = fmaf(p11, q[11], a##oc); \
        a##oc = fmaf(p12, q[12], a##oc); a##oc = fmaf(p13, q[13], a##oc); \
        a##oc = fmaf(p14, q[14], a##oc); a##oc = fmaf(p15, q[15], a##oc); }
        R8X(FMAOC)
#undef FMAOC
    }
    float* o = out + (size_t)b * (16 * 4096) + (size_t)ocb * 4096 + oy * 64 + ox;
#define STO(oc) o[oc * 4096] = fmaxf(a##oc, 0.f);
    R8X(STO)
#undef STO
}

// ---------------- residual block — oc-split halves, 2048 blocks, 8 acc/thread ----------------
__global__ __launch_bounds__(256) void res_k(const float* __restrict__ in, const float* __restrict__ w,
                                             const float* __restrict__ bias, float* __restrict__ out) {
    int half = blockIdx.x >> 10;
    int idx  = (blockIdx.x & 1023) * 256 + threadIdx.x;   // 64*64*64
    int ox = idx & 63;
    int oy = (idx >> 6) & 63;
    int b  = idx >> 12;
    int ocb = half * 8;
    const float* xin = in + (size_t)b * 65536;
    const float* wb  = w + (size_t)ocb * 144;
#define DECLB(i) float a##i = bias[ocb + i];
    R8X(DECLB)
#undef DECLB
    bool yt = (oy > 0), yb = (oy < 63);
    bool xl = (ox > 0), xr = (ox < 63);
    for (int ic = 0; ic < 16; ++ic) {
        const float* xb = xin + ic * 4096 + (oy - 1) * 64 + (ox - 1);
        float pa0 = (yt && xl) ? xb[0]       : 0.f;
        float pa1 =  yt        ? xb[1]       : 0.f;
        float pa2 = (yt && xr) ? xb[2]       : 0.f;
        float pb0 =  xl        ? xb[64 + 0]  : 0.f;
        float pb1 =              xb[64 + 1];
        float pb2 =  xr        ? xb[64 + 2]  : 0.f;
        float pc0 = (yb && xl) ? xb[128 + 0] : 0.f;
        float pc1 =  yb        ? xb[128 + 1] : 0.f;
        float pc2 = (yb && xr) ? xb[128 + 2] : 0.f;
        const float* wp = wb + ic * 9;
#define FMAR(oc) { const float* q = wp + oc * 144; \
        a##oc = fmaf(pa0, q[0], a##oc); a##oc = fmaf(pa1, q[1], a##oc); a##oc = fmaf(pa2, q[2], a##oc); \
        a##oc = fmaf(pb0, q[3], a##oc); a##oc = fmaf(pb1, q[4], a##oc); a##oc = fmaf(pb2, q[5], a##oc); \
        a##oc = fmaf(pc0, q[6], a##oc); a##oc = fmaf(pc1, q[7], a##oc); a##oc = fmaf(pc2, q[8], a##oc); }
        R8X(FMAR)
#undef FMAR
    }
    float* o        = out + (size_t)b * 65536 + (size_t)ocb * 4096 + oy * 64 + ox;
    const float* rr = xin + (size_t)ocb * 4096 + oy * 64 + ox;
#define RSTO(oc) o[oc * 4096] = rr[oc * 4096] + fmaxf(a##oc, 0.f);
    R8X(RSTO)
#undef RSTO
}

// ---------------- res variant for dr2: writes bf16 CHANNEL-LAST (64,64,64,16) ----------------
__global__ __launch_bounds__(256) void res_bf16_k(const float* __restrict__ in, const float* __restrict__ w,
                                                  const float* __restrict__ bias, unsigned short* __restrict__ outb) {
    int half = blockIdx.x >> 10;
    int idx  = (blockIdx.x & 1023) * 256 + threadIdx.x;   // 64*64*64
    int ox = idx & 63;
    int oy = (idx >> 6) & 63;
    int b  = idx >> 12;
    int ocb = half * 8;
    const float* xin = in + (size_t)b * 65536;
    const float* wb  = w + (size_t)ocb * 144;
#define DECLB(i) float a##i = bias[ocb + i];
    R8X(DECLB)
#undef DECLB
    bool yt = (oy > 0), yb = (oy < 63);
    bool xl = (ox > 0), xr = (ox < 63);
    for (int ic = 0; ic < 16; ++ic) {
        const float* xb = xin + ic * 4096 + (oy - 1) * 64 + (ox - 1);
        float pa0 = (yt && xl) ? xb[0]       : 0.f;
        float pa1 =  yt        ? xb[1]       : 0.f;
        float pa2 = (yt && xr) ? xb[2]       : 0.f;
        float pb0 =  xl        ? xb[64 + 0]  : 0.f;
        float pb1 =              xb[64 + 1];
        float pb2 =  xr        ? xb[64 + 2]  : 0.f;
        float pc0 = (yb && xl) ? xb[128 + 0] : 0.f;
        float pc1 =  yb        ? xb[128 + 1] : 0.f;
        float pc2 = (yb && xr) ? xb[128 + 2] : 0.f;
        const float* wp = wb + ic * 9;
#define FMAR(oc) { const float* q = wp + oc * 144; \
        a##oc = fmaf(pa0, q[0], a##oc); a##oc = fmaf(pa1, q[1], a##oc); a##oc = fmaf(pa2, q[2], a##oc); \
        a##oc = fmaf(pb0, q[3], a##oc); a##oc = fmaf(pb1, q[4], a##oc); a##oc = fmaf(pb2, q[5], a##oc); \
        a##oc = fmaf(pc0, q[6], a##oc); a##oc = fmaf(pc1, q[7], a##oc); a##oc = fmaf(pc2, q[8], a##oc); }
        R8X(FMAR)
#undef FMAR
    }
    const float* rr = xin + (size_t)ocb * 4096 + oy * 64 + ox;
    u16x8 pk;
#define PK(oc) pk[oc] = f2bf(rr[oc * 4096] + fmaxf(a##oc, 0.f));
    R8X(PK)
#undef PK
    *(u16x8*)(outb + (((size_t)b * 4096) + oy * 64 + ox) * 16 + ocb) = pk;
}

// ---------------- VQ: rows of 16 contiguous floats (raw NCHW flatten), K=64 ----------------
__global__ __launch_bounds__(256) void vq_k(const float* __restrict__ h, const float* __restrict__ cb,
                                            float* __restrict__ q, float* __restrict__ idx_out) {
    __shared__ float cbs[1024];  // 64 x 16
    __shared__ float cn[64];
    for (int i = threadIdx.x; i < 1024; i += 256) cbs[i] = cb[i];
    __syncthreads();
    if (threadIdx.x < 64) {
        float s = 0.f;
#pragma unroll
        for (int d = 0; d < 16; ++d) { float v = cbs[threadIdx.x * 16 + d]; s = fmaf(v, v, s); }
        cn[threadIdx.x] = s;
    }
    __syncthreads();
    int r = blockIdx.x * 256 + threadIdx.x;   // 262144 rows
    float f[16];
    const float4* hp = (const float4*)(h + (size_t)r * 16);
#pragma unroll
    for (int j = 0; j < 4; ++j) {
        float4 v = hp[j];
        f[j * 4 + 0] = v.x; f[j * 4 + 1] = v.y; f[j * 4 + 2] = v.z; f[j * 4 + 3] = v.w;
    }
    float best = 3.4e38f;
    int bi = 0;
    for (int k = 0; k < 64; ++k) {
        float dot = 0.f;
#pragma unroll
        for (int d = 0; d < 16; ++d) dot = fmaf(f[d], cbs[k * 16 + d], dot);
        float dist = cn[k] - 2.f * dot;   // +||f||^2 is per-row constant, argmin-invariant
        if (dist < best) { best = dist; bi = k; }
    }
    float4* qp = (float4*)(q + (size_t)r * 16);
    const float4* cp = (const float4*)(cbs + bi * 16);
#pragma unroll
    for (int j = 0; j < 4; ++j) qp[j] = cp[j];
    idx_out[r] = (float)bi;
}

// ---------------- tconv1 via MFMA: per parity class GEMM M=262144 N=16 K=64 ----------------
// A[px][k] (k=tap*16+ic) from bf16 ch-last (64,64,64,16); B' = W'[k][oc]; C -> f1 ch-last fp32.
// Frag mapping (m89/m92-verified family): A row = lane&15 (px), k = (lane>>4)*8+j (8 consec, 16B);
// B^T row = lane&15 (oc), same k; C/D col = lane&15 (oc), row = (lane>>4)*4+reg (px).
__global__ __launch_bounds__(256) void tconv1_mfma_k(const unsigned short* __restrict__ xb,
                                                     const float* __restrict__ w1, const float* __restrict__ bia,
                                                     float* __restrict__ out) {
    int cls = blockIdx.x >> 9;           // 4 classes x 512 blocks
    int bb  = blockIdx.x & 511;
    int DY = cls >> 1, DX = cls & 1;
    int wid  = threadIdx.x >> 6;
    int lane = threadIdx.x & 63;
    int oc = lane & 15;                  // B col / C col; also A px-row index
    int kg = lane >> 4;                  // 0..3: k-group of 8

    // B-frags (once per wave): b[m][j] = bf16(W'[k = m*32 + kg*8 + j][oc])
    bf16x8 bfr0, bfr1;
    float accb = bia[oc];
#pragma unroll
    for (int m = 0; m < 2; ++m) {
        int tap = 2 * m + (kg >> 1);
        int ty = tap >> 1, tx = tap & 1;
        int koff = (3 - DY - 2 * ty) * 4 + (3 - DX - 2 * tx);
        int ic0 = (kg & 1) * 8;
        bf16x8 t;
#pragma unroll
        for (int j = 0; j < 8; ++j)
            t[j] = (short)f2bf(w1[(ic0 + j) * 256 + oc * 16 + koff]);
        if (m == 0) bfr0 = t; else bfr1 = t;
    }

    int Wc = bb * 4 + wid;               // 0..2047 within class
    for (int t = 0; t < 8; ++t) {
        int tile = Wc * 8 + t;           // 0..16383
        int v0  = (tile & 3) * 16;
        int u   = (tile >> 2) & 63;
        int img = tile >> 8;
        const unsigned short* xi = xb + (size_t)img * 65536;   // 4096 px x 16 ch
        f32x4 acc = { accb, accb, accb, accb };
#pragma unroll
        for (int m = 0; m < 2; ++m) {
            int tap = 2 * m + (kg >> 1);
            int ty = tap >> 1, tx = tap & 1;
            int jy = u + DY - 1 + ty;                 // tile-uniform
            int jx = v0 + oc + DX - 1 + tx;           // per-lane (oc == lane&15 == px row)
            bf16x8 a = { 0, 0, 0, 0, 0, 0, 0, 0 };
            if (jy >= 0 && jy < 64 && jx >= 0 && jx < 64) {
                int ic0 = (kg & 1) * 8;
                a = *(const bf16x8*)(xi + ((jy * 64 + jx) * 16 + ic0));
            }
            acc = __builtin_amdgcn_mfma_f32_16x16x32_bf16(a, (m == 0 ? bfr0 : bfr1), acc, 0, 0, 0);
        }
        int my = 2 * u + DY;
#pragma unroll
        for (int r = 0; r < 4; ++r) {
            int pxr = kg * 4 + r;                     // C row
            int mx  = 2 * (v0 + pxr) + DX;
            out[(((size_t)img * 16384) + my * 128 + mx) * 16 + oc] = fmaxf(acc[r], 0.f);
        }
    }
}

// ---------------- tconv2: ConvTranspose2d 16->1, k4 s2 p1, 128->256 ----------------
#define P2 20
__global__ __launch_bounds__(256) void tconv2_k(const float* __restrict__ f1,
                                                const float* __restrict__ w2, const float* __restrict__ b2,
                                                float* __restrict__ out) {
    __shared__ float s1[324 * P2];       // [pixel(18x18)][16 ch + pad4]
    __shared__ float ws2[256];           // (ic,1,4,4)
    __shared__ float b2s;
    if (threadIdx.x < 256) ws2[threadIdx.x] = w2[threadIdx.x];
    if (threadIdx.x == 0) b2s = b2[0];

    int tile = blockIdx.x & 63;
    int b    = blockIdx.x >> 6;
    int Y0 = (tile >> 3) * 32;
    int X0 = (tile & 7) * 32;
    int m0 = (Y0 >> 1) - 1;
    int n0 = (X0 >> 1) - 1;
    const float* fb = f1 + (size_t)b * 262144;   // (128,128,16) channel-last

    for (int i = threadIdx.x; i < 5184; i += 256) {
        int p  = i >> 4;
        int ic = i & 15;
        int my = m0 + p / 18;
        int mx = n0 + p % 18;
        float v = 0.f;
        if (my >= 0 && my < 128 && mx >= 0 && mx < 128)
            v = fb[((size_t)(my * 128 + mx)) * 16 + ic];
        s1[p * P2 + ic] = v;
    }
    __syncthreads();

    int ly0 = threadIdx.x >> 5;
    int lx  = threadIdx.x & 31;
    int gx  = X0 + lx;
    int kyb = (Y0 + ly0 + 1) & 1;
    int kxb = (gx + 1) & 1;
    float wr[2][2][16];
#pragma unroll
    for (int a = 0; a < 2; ++a) {
#pragma unroll
        for (int c = 0; c < 2; ++c) {
            int ky = kyb + 2 * a, kx = kxb + 2 * c;
#pragma unroll
            for (int ic = 0; ic < 16; ++ic)
                wr[a][c][ic] = ws2[ic * 16 + ky * 4 + kx];
        }
    }
    int sx[2];
#pragma unroll
    for (int c = 0; c < 2; ++c) sx[c] = ((gx + 1 - (kxb + 2 * c)) >> 1) - n0;

#pragma unroll
    for (int r = 0; r < 4; ++r) {
        int gy = Y0 + ly0 + 8 * r;
        float acc = b2s;
#pragma unroll
        for (int a = 0; a < 2; ++a) {
            int sy = ((gy + 1 - (kyb + 2 * a)) >> 1) - m0;
#pragma unroll
            for (int c = 0; c < 2; ++c) {
                const float4* sp4 = (const float4*)&s1[(sy * 18 + sx[c]) * P2];
#pragma unroll
                for (int j = 0; j < 4; ++j) {
                    float4 v = sp4[j];
                    acc = fmaf(v.x, wr[a][c][j * 4 + 0], acc);
                    acc = fmaf(v.y, wr[a][c][j * 4 + 1], acc);
                    acc = fmaf(v.z, wr[a][c][j * 4 + 2], acc);
                    acc = fmaf(v.w, wr[a][c][j * 4 + 3], acc);
                }
            }
        }
        out[(size_t)b * 65536 + gy * 256 + gx] = acc;
    }
}

extern "C" void kernel_launch(void* const* d_in, const int* in_sizes, int n_in,
                              void* d_out, int out_size, void* d_ws, size_t ws_size,
                              hipStream_t stream) {
    const float* x    = (const float*)d_in[0];
    const float* c1w  = (const float*)d_in[1];
    const float* c1b  = (const float*)d_in[2];
    const float* c2w  = (const float*)d_in[3];
    const float* c2b  = (const float*)d_in[4];
    const float* er1w = (const float*)d_in[5];
    const float* er1b = (const float*)d_in[6];
    const float* er2w = (const float*)d_in[7];
    const float* er2b = (const float*)d_in[8];
    const float* cb   = (const float*)d_in[9];
    const float* dr1w = (const float*)d_in[10];
    const float* dr1b = (const float*)d_in[11];
    const float* dr2w = (const float*)d_in[12];
    const float* dr2b = (const float*)d_in[13];
    const float* t1w  = (const float*)d_in[14];
    const float* t1b  = (const float*)d_in[15];
    const float* t2w  = (const float*)d_in[16];
    const float* t2b  = (const float*)d_in[17];

    float* f1 = (float*)d_ws;                                // 64 MiB: dec ch-last fp32
    float* f2 = (float*)((char*)d_ws + 67108864);            // (64,16,64,64)
    float* f3 = (float*)((char*)d_ws + 67108864 + 16777216); // (64,16,64,64) / bf16 ch-last (8.4 MiB)

    float* out     = (float*)d_out;                          // decoded: 4,194,304 f32
    float* idx_out = out + 4194304;                          // indices: 262,144 f32

    conv1_k     <<<4096, 256, 0, stream>>>(x, c1w, c1b, f1);
    conv2_k     <<<2048, 256, 0, stream>>>(f1, c2w, c2b, f2);
    res_k       <<<2048, 256, 0, stream>>>(f2, er1w, er1b, f3);  // er1
    res_k       <<<2048, 256, 0, stream>>>(f3, er2w, er2b, f2);  // er2
    vq_k        <<<1024, 256, 0, stream>>>(f2, cb, f3, idx_out); // quantized -> f3
    res_k       <<<2048, 256, 0, stream>>>(f3, dr1w, dr1b, f2);  // dr1
    res_bf16_k  <<<2048, 256, 0, stream>>>(f2, dr2w, dr2b, (unsigned short*)f3);  // dr2 -> bf16 ch-last
    tconv1_mfma_k<<<2048, 256, 0, stream>>>((const unsigned short*)f3, t1w, t1b, f1);
    tconv2_k    <<<4096, 256, 0, stream>>>(f1, t2w, t2b, out);
}